// Round 1
// baseline (1322.320 us; speedup 1.0000x reference)
//
#include <hip/hip_runtime.h>

#define BB 2
#define CC 16
#define BC 32
#define FF 256
#define WW 512
#define HH 8
#define DH 32
#define EE 1024

__device__ __forceinline__ float bf2f(unsigned short u) {
    union { unsigned int i; float f; } x; x.i = ((unsigned int)u) << 16; return x.f;
}
__device__ __forceinline__ unsigned short f2bf(float f) {
    union { float f; unsigned int i; } x; x.f = f;
    unsigned int r = x.i + 0x7fffu + ((x.i >> 16) & 1u);   // round-nearest-even
    return (unsigned short)(r >> 16);
}

// ---------------- LayerNorm over f (axis stride W) ----------------
// grid (BC, 2), block 256: one thread per w column
__global__ __launch_bounds__(256) void ln_kernel(
    const float* __restrict__ x, const float* __restrict__ g,
    const float* __restrict__ bta, unsigned short* __restrict__ out) {
    int bc = blockIdx.x;
    int c = bc & (CC - 1);
    int w = blockIdx.y * 256 + threadIdx.x;
    const float* xp = x + ((size_t)bc * FF) * WW + w;
    float s = 0.f, s2 = 0.f;
#pragma unroll 4
    for (int f = 0; f < FF; ++f) { float t = xp[(size_t)f * WW]; s += t; s2 += t * t; }
    float m = s * (1.f / FF);
    float v = s2 * (1.f / FF) - m * m;
    float r = rsqrtf(v + 1e-5f);
    unsigned short* op = out + ((size_t)bc * FF) * WW + w;
    const float* gp = g + c * FF;
    const float* bp = bta + c * FF;
#pragma unroll 4
    for (int f = 0; f < FF; ++f) {
        float t = (xp[(size_t)f * WW] - m) * r * gp[f] + bp[f];
        op[(size_t)f * WW] = f2bf(t);
    }
}

// ---------------- fused 3x conv3x3 (NCHW, OIHW, pad 1) ----------------
// grid (BC(b,co), FF, 2), block 256
__global__ __launch_bounds__(256) void conv3_kernel(
    const unsigned short* __restrict__ n1,
    const float* __restrict__ wq, const float* __restrict__ wk, const float* __restrict__ wv,
    unsigned short* __restrict__ oq, unsigned short* __restrict__ ok, unsigned short* __restrict__ ov) {
    int bco = blockIdx.x; int b = bco >> 4; int co = bco & 15;
    int f = blockIdx.y;
    int w = blockIdx.z * 256 + threadIdx.x;
    float aq = 0.f, ak = 0.f, av = 0.f;
    for (int ci = 0; ci < CC; ++ci) {
        const unsigned short* ip = n1 + ((size_t)(b * CC + ci) * FF) * WW;
        const float* wqp = wq + (co * CC + ci) * 9;
        const float* wkp = wk + (co * CC + ci) * 9;
        const float* wvp = wv + (co * CC + ci) * 9;
#pragma unroll
        for (int kh = 0; kh < 3; ++kh) {
            int fy = f + kh - 1;
            if (fy < 0 || fy >= FF) continue;
            const unsigned short* rp = ip + (size_t)fy * WW;
#pragma unroll
            for (int kw = 0; kw < 3; ++kw) {
                int wx = w + kw - 1;
                if (wx < 0 || wx >= WW) continue;
                float t = bf2f(rp[wx]);
                aq += t * wqp[kh * 3 + kw];
                ak += t * wkp[kh * 3 + kw];
                av += t * wvp[kh * 3 + kw];
            }
        }
    }
    size_t o = ((size_t)(b * CC + co) * FF + f) * WW + w;
    oq[o] = f2bf(aq);
    ok[o] = f2bf(ak);
    ov[o] = f2bf(av);
}

// ---------------- per-channel GEMM: y[bc,g,w] = sum_f W[c,g,f] * T[bc,f,w] ----------------
// grid (BC, M/8), block 256: each thread 2 w-columns x 8 g-rows
// MODE 0: write bf16; MODE 1: of[o] += acc (f32 in-place)
template <int K, int MODE>
__global__ __launch_bounds__(256) void chan_gemm(
    const unsigned short* __restrict__ T, const float* __restrict__ Wt,
    unsigned short* __restrict__ ob, float* __restrict__ of, int M) {
    int bc = blockIdx.x; int c = bc & (CC - 1);
    int g0 = blockIdx.y * 8;
    int tx = threadIdx.x;
    int w = tx * 2;
    const unsigned short* tp = T + ((size_t)bc * K) * WW;
    const float* wp = Wt + ((size_t)c * M + g0) * K;
    float a0[8] = {0.f,0.f,0.f,0.f,0.f,0.f,0.f,0.f};
    float a1[8] = {0.f,0.f,0.f,0.f,0.f,0.f,0.f,0.f};
#pragma unroll 2
    for (int f = 0; f < K; ++f) {
        const ushort2 u = *reinterpret_cast<const ushort2*>(tp + (size_t)f * WW + w);
        float t0 = bf2f(u.x), t1 = bf2f(u.y);
#pragma unroll
        for (int g = 0; g < 8; ++g) {
            float ww = wp[(size_t)g * K + f];
            a0[g] += ww * t0; a1[g] += ww * t1;
        }
    }
#pragma unroll
    for (int g = 0; g < 8; ++g) {
        size_t o = ((size_t)bc * M + g0 + g) * WW + w;
        if (MODE == 0) {
            ushort2 pack;
            pack.x = f2bf(a0[g]); pack.y = f2bf(a1[g]);
            *reinterpret_cast<ushort2*>(ob + o) = pack;
        } else {
            float2* p = reinterpret_cast<float2*>(of + o);
            float2 v = *p; v.x += a0[g]; v.y += a1[g]; *p = v;
        }
    }
}

// ---------------- qk: qk[bc,h,qw,kw] = (1/16) sum_d q[d,qw] k[d,kw] ----------------
// grid (BC*HH, 8), block 256: 64 qw rows per block, all 512 kw
__global__ __launch_bounds__(256) void qk_kernel(
    const unsigned short* __restrict__ q, const unsigned short* __restrict__ k,
    float* __restrict__ qko) {
    int bch = blockIdx.x;
    int qt = blockIdx.y;
    int tx = threadIdx.x;
    int bc = bch >> 3, h = bch & 7;
    __shared__ unsigned short kl[32 * 512];
    __shared__ __align__(16) float ql[32][64];
    const unsigned short* kp = k + ((size_t)bc * FF + h * DH) * WW;
    const unsigned short* qp = q + ((size_t)bc * FF + h * DH) * WW + qt * 64;
    for (int i = tx * 4; i < 32 * 512; i += 1024)
        *reinterpret_cast<ushort4*>(kl + i) = *reinterpret_cast<const ushort4*>(kp + i);
    for (int i = tx; i < 32 * 64; i += 256) {
        int d = i >> 6, qw = i & 63;
        ql[d][qw] = bf2f(qp[(size_t)d * WW + qw]);
    }
    __syncthreads();
    float kr0[32], kr1[32];
#pragma unroll
    for (int d = 0; d < 32; ++d) {
        kr0[d] = bf2f(kl[d * 512 + tx]);
        kr1[d] = bf2f(kl[d * 512 + tx + 256]);
    }
    float* orow = qko + ((size_t)bch * WW + qt * 64) * WW;
    for (int q4 = 0; q4 < 16; ++q4) {
        float ax[4] = {0.f,0.f,0.f,0.f};
        float ay[4] = {0.f,0.f,0.f,0.f};
#pragma unroll
        for (int d = 0; d < 32; ++d) {
            float4 qv = *reinterpret_cast<const float4*>(&ql[d][q4 * 4]);
            ax[0] += qv.x * kr0[d]; ay[0] += qv.x * kr1[d];
            ax[1] += qv.y * kr0[d]; ay[1] += qv.y * kr1[d];
            ax[2] += qv.z * kr0[d]; ay[2] += qv.z * kr1[d];
            ax[3] += qv.w * kr0[d]; ay[3] += qv.w * kr1[d];
        }
#pragma unroll
        for (int j = 0; j < 4; ++j) {
            orow[(size_t)(q4 * 4 + j) * WW + tx] = ax[j] * 0.0625f;
            orow[(size_t)(q4 * 4 + j) * WW + tx + 256] = ay[j] * 0.0625f;
        }
    }
}

// ---------------- softmax over kw + PV ----------------
// grid (BC*HH, 8), block 256
__global__ __launch_bounds__(256) void attn_pv(
    const float* __restrict__ qk, const unsigned short* __restrict__ v,
    unsigned short* __restrict__ a) {
    int bch = blockIdx.x, qt = blockIdx.y, tx = threadIdx.x;
    int bc = bch >> 3, h = bch & 7;
    __shared__ unsigned short vl[512][34];
    __shared__ float pl[512];
    __shared__ float red[8][33];
    __shared__ float wred[8];
    const unsigned short* vp = v + ((size_t)bc * FF + h * DH) * WW;
    for (int i = tx * 4; i < 32 * 512; i += 1024) {
        ushort4 u = *reinterpret_cast<const ushort4*>(vp + i);
        int d = i >> 9, kw = i & 511;
        vl[kw][d] = u.x; vl[kw + 1][d] = u.y; vl[kw + 2][d] = u.z; vl[kw + 3][d] = u.w;
    }
    __syncthreads();
    int g = tx >> 5, d = tx & 31;
    int lane = tx & 63, wid = tx >> 6;
    for (int r = 0; r < 64; ++r) {
        int qw = qt * 64 + r;
        const float* row = qk + ((size_t)bch * WW + qw) * WW;
        float x0 = row[tx], x1 = row[tx + 256];
        float m = fmaxf(x0, x1);
#pragma unroll
        for (int s = 32; s; s >>= 1) m = fmaxf(m, __shfl_xor(m, s));
        if (lane == 0) wred[wid] = m;
        __syncthreads();
        m = fmaxf(fmaxf(wred[0], wred[1]), fmaxf(wred[2], wred[3]));
        float e0 = __expf(x0 - m), e1 = __expf(x1 - m);
        pl[tx] = e0; pl[tx + 256] = e1;
        float s2 = e0 + e1;
#pragma unroll
        for (int s = 32; s; s >>= 1) s2 += __shfl_xor(s2, s);
        if (lane == 0) wred[4 + wid] = s2;
        __syncthreads();
        // PV: group g sums kw chunk [g*64, g*64+64), output feature d
        float acc = 0.f;
#pragma unroll 8
        for (int i = 0; i < 64; ++i) {
            int kw = g * 64 + i;
            acc += pl[kw] * bf2f(vl[kw][d]);
        }
        red[g][d] = acc;
        __syncthreads();
        if (tx < 32) {
            float ssum = 0.f;
#pragma unroll
            for (int gg = 0; gg < 8; ++gg) ssum += red[gg][tx];
            float denom = wred[4] + wred[5] + wred[6] + wred[7];
            a[((size_t)bc * FF + h * DH + tx) * WW + qw] = f2bf(ssum / denom);
        }
        __syncthreads();
    }
}

// ---------------- depthwise 16-ch mix + residual: h = x + sum_c wdw[o,c]*pw[b,c,:,:] ----------------
__global__ __launch_bounds__(256) void dwres_kernel(
    const unsigned short* __restrict__ pw, const float* __restrict__ wdw,
    const float* __restrict__ x, float* __restrict__ h) {
    size_t idx = (size_t)blockIdx.x * 256 + threadIdx.x;
    size_t fw = idx & 131071;
    int o = (int)((idx >> 17) & 15);
    int b = (int)(idx >> 21);
    const float* wp = wdw + o * CC;
    float s = 0.f;
#pragma unroll
    for (int ci = 0; ci < CC; ++ci)
        s += wp[ci] * bf2f(pw[(((size_t)(b * CC + ci)) << 17) + fw]);
    h[idx] = x[idx] + s;
}

// ---------------- depthwise 16-ch mix + SquaredReLU ----------------
__global__ __launch_bounds__(256) void dwsq_kernel(
    const unsigned short* __restrict__ u1, const float* __restrict__ wdw,
    unsigned short* __restrict__ u2) {
    size_t idx = (size_t)blockIdx.x * 256 + threadIdx.x;
    size_t gw = idx & 524287;
    int o = (int)((idx >> 19) & 15);
    int b = (int)(idx >> 23);
    const float* wp = wdw + o * CC;
    float s = 0.f;
#pragma unroll
    for (int ci = 0; ci < CC; ++ci)
        s += wp[ci] * bf2f(u1[(((size_t)(b * CC + ci)) << 19) + gw]);
    s = fmaxf(s, 0.f);
    u2[idx] = f2bf(s * s);
}

extern "C" void kernel_launch(void* const* d_in, const int* in_sizes, int n_in,
                              void* d_out, int out_size, void* d_ws, size_t ws_size,
                              hipStream_t stream) {
    const float* x      = (const float*)d_in[0];
    const float* conv_q = (const float*)d_in[1];
    const float* conv_k = (const float*)d_in[2];
    const float* conv_v = (const float*)d_in[3];
    const float* wq     = (const float*)d_in[4];
    const float* wk     = (const float*)d_in[5];
    const float* wv     = (const float*)d_in[6];
    const float* wo_pw  = (const float*)d_in[7];
    const float* wo_dw  = (const float*)d_in[8];
    const float* g1     = (const float*)d_in[9];
    const float* b1     = (const float*)d_in[10];
    const float* g2     = (const float*)d_in[11];
    const float* b2     = (const float*)d_in[12];
    const float* w1_pw  = (const float*)d_in[13];
    const float* w1_dw  = (const float*)d_in[14];
    const float* w2_pw  = (const float*)d_in[15];

    float* hout  = (float*)d_out;                 // (2,16,256,512) f32
    float* qkout = (float*)d_out + 4194304;       // (2,16,8,512,512) f32

    // workspace carve (liveness-aliased; needs 88 MB)
    char* ws = (char*)d_ws;
    const size_t MB8 = (size_t)8 << 20;
    unsigned short* n1 = (unsigned short*)(ws + 0 * MB8);   // later: a
    unsigned short* cq = (unsigned short*)(ws + 1 * MB8);   // later: pw
    unsigned short* ck = (unsigned short*)(ws + 2 * MB8);   // later: n2
    unsigned short* cv = (unsigned short*)(ws + 3 * MB8);
    unsigned short* qb = (unsigned short*)(ws + 4 * MB8);
    unsigned short* kb = (unsigned short*)(ws + 5 * MB8);
    unsigned short* vb = (unsigned short*)(ws + 6 * MB8);
    unsigned short* u1 = (unsigned short*)(ws + 3 * MB8);   // 32 MB (aliases cv,qb,kb,vb after attn)
    unsigned short* u2 = (unsigned short*)(ws + 7 * MB8);   // 32 MB
    unsigned short* ab  = n1;
    unsigned short* pwb = cq;
    unsigned short* n2  = ck;

    ln_kernel<<<dim3(BC, 2), 256, 0, stream>>>(x, g1, b1, n1);
    conv3_kernel<<<dim3(BC, FF, 2), 256, 0, stream>>>(n1, conv_q, conv_k, conv_v, cq, ck, cv);
    chan_gemm<256, 0><<<dim3(BC, 32), 256, 0, stream>>>(cq, wq, qb, nullptr, 256);
    chan_gemm<256, 0><<<dim3(BC, 32), 256, 0, stream>>>(ck, wk, kb, nullptr, 256);
    chan_gemm<256, 0><<<dim3(BC, 32), 256, 0, stream>>>(cv, wv, vb, nullptr, 256);
    qk_kernel<<<dim3(BC * HH, 8), 256, 0, stream>>>(qb, kb, qkout);
    attn_pv<<<dim3(BC * HH, 8), 256, 0, stream>>>(qkout, vb, ab);
    chan_gemm<256, 0><<<dim3(BC, 32), 256, 0, stream>>>(ab, wo_pw, pwb, nullptr, 256);
    dwres_kernel<<<dim3(16384), 256, 0, stream>>>(pwb, wo_dw, x, hout);
    ln_kernel<<<dim3(BC, 2), 256, 0, stream>>>(hout, g2, b2, n2);
    chan_gemm<256, 0><<<dim3(BC, 128), 256, 0, stream>>>(n2, w1_pw, u1, nullptr, 1024);
    dwsq_kernel<<<dim3(65536), 256, 0, stream>>>(u1, w1_dw, u2);
    chan_gemm<1024, 1><<<dim3(BC, 32), 256, 0, stream>>>(u2, w2_pw, nullptr, hout, 256);
}

// Round 2
// 631.007 us; speedup vs baseline: 2.0956x; 2.0956x over previous
//
#include <hip/hip_runtime.h>

#define BB 2
#define CC 16
#define BC 32
#define FF 256
#define WW 512
#define HH 8
#define DH 32

using bf16x8 = __attribute__((ext_vector_type(8))) __bf16;
using f32x4  = __attribute__((ext_vector_type(4))) float;
using us8    = __attribute__((ext_vector_type(8))) unsigned short;
using us4    = __attribute__((ext_vector_type(4))) unsigned short;

__device__ __forceinline__ float bf2f(unsigned short u) {
    union { unsigned int i; float f; } x; x.i = ((unsigned int)u) << 16; return x.f;
}
__device__ __forceinline__ unsigned short f2bf(float f) {
    union { float f; unsigned int i; } x; x.f = f;
    unsigned int r = x.i + 0x7fffu + ((x.i >> 16) & 1u);   // round-nearest-even
    return (unsigned short)(r >> 16);
}
__device__ __forceinline__ f32x4 mfma16(bf16x8 a, bf16x8 b, f32x4 c) {
    return __builtin_amdgcn_mfma_f32_16x16x32_bf16(a, b, c, 0, 0, 0);
}

// ---------------- LayerNorm over f (axis stride W) ----------------
__global__ __launch_bounds__(256) void ln_kernel(
    const float* __restrict__ x, const float* __restrict__ g,
    const float* __restrict__ bta, unsigned short* __restrict__ out) {
    int bc = blockIdx.x;
    int c = bc & (CC - 1);
    int w = blockIdx.y * 256 + threadIdx.x;
    const float* xp = x + ((size_t)bc * FF) * WW + w;
    float s = 0.f, s2 = 0.f;
#pragma unroll 4
    for (int f = 0; f < FF; ++f) { float t = xp[(size_t)f * WW]; s += t; s2 += t * t; }
    float m = s * (1.f / FF);
    float v = s2 * (1.f / FF) - m * m;
    float r = rsqrtf(v + 1e-5f);
    unsigned short* op = out + ((size_t)bc * FF) * WW + w;
    const float* gp = g + c * FF;
    const float* bp = bta + c * FF;
#pragma unroll 4
    for (int f = 0; f < FF; ++f) {
        float t = (xp[(size_t)f * WW] - m) * r * gp[f] + bp[f];
        op[(size_t)f * WW] = f2bf(t);
    }
}

// ---------------- fused 3x conv3x3 (NCHW, OIHW, pad 1) ----------------
__global__ __launch_bounds__(256) void conv3_kernel(
    const unsigned short* __restrict__ n1,
    const float* __restrict__ wq, const float* __restrict__ wk, const float* __restrict__ wv,
    unsigned short* __restrict__ oq, unsigned short* __restrict__ ok, unsigned short* __restrict__ ov) {
    int bco = blockIdx.x; int b = bco >> 4; int co = bco & 15;
    int f = blockIdx.y;
    int w = blockIdx.z * 256 + threadIdx.x;
    float aq = 0.f, ak = 0.f, av = 0.f;
    for (int ci = 0; ci < CC; ++ci) {
        const unsigned short* ip = n1 + ((size_t)(b * CC + ci) * FF) * WW;
        const float* wqp = wq + (co * CC + ci) * 9;
        const float* wkp = wk + (co * CC + ci) * 9;
        const float* wvp = wv + (co * CC + ci) * 9;
#pragma unroll
        for (int kh = 0; kh < 3; ++kh) {
            int fy = f + kh - 1;
            if (fy < 0 || fy >= FF) continue;
            const unsigned short* rp = ip + (size_t)fy * WW;
#pragma unroll
            for (int kw = 0; kw < 3; ++kw) {
                int wx = w + kw - 1;
                if (wx < 0 || wx >= WW) continue;
                float t = bf2f(rp[wx]);
                aq += t * wqp[kh * 3 + kw];
                ak += t * wkp[kh * 3 + kw];
                av += t * wvp[kh * 3 + kw];
            }
        }
    }
    size_t o = ((size_t)(b * CC + co) * FF + f) * WW + w;
    oq[o] = f2bf(aq);
    ok[o] = f2bf(ak);
    ov[o] = f2bf(av);
}

// ---------------- MFMA per-channel GEMM ----------------
// y[bc,g,w] = sum_f W[c,g,f] * T[bc,f,w]; tile 64g x 64w, BK=64, 4 waves (2x2).
// MODE 0: bf16 store; MODE 1: f32 += into of.
template <int K, int M, int MODE>
__global__ __launch_bounds__(256, 4) void mgemm(
    const unsigned short* __restrict__ T, const float* __restrict__ Wt,
    unsigned short* __restrict__ ob, float* __restrict__ of) {
    __shared__ unsigned short Al[64 * 64];
    __shared__ unsigned short Bl[64 * 64];
    const int bc = blockIdx.x, c = bc & 15;
    const int G0 = blockIdx.y * 64, W0 = blockIdx.z * 64;
    const int tx = threadIdx.x;
    const int lane = tx & 63, wid = tx >> 6;
    const int lr = lane & 15, lg = lane >> 4;
    const int wr = wid >> 1, wc = wid & 1;

    const unsigned short* Tb = T + (size_t)bc * K * WW;
    const float* Wb = Wt + ((size_t)c * M + G0) * K;

    f32x4 acc[2][2];
#pragma unroll
    for (int i = 0; i < 2; ++i)
#pragma unroll
        for (int j = 0; j < 2; ++j) acc[i][j] = (f32x4){0.f, 0.f, 0.f, 0.f};

    const int ag = tx >> 2, aseg = tx & 3;
    const int bfr = tx >> 3, bws = tx & 7;

    for (int f0 = 0; f0 < K; f0 += 64) {
        // stage A: W[g][f] f32 -> bf16, swizzled rows of 128B
        {
            const float* wrow = Wb + (size_t)ag * K + f0 + aseg * 16;
            float4 x0 = *(const float4*)(wrow + 0);
            float4 x1 = *(const float4*)(wrow + 4);
            float4 x2 = *(const float4*)(wrow + 8);
            float4 x3 = *(const float4*)(wrow + 12);
            uint4 p0, p1;
            p0.x = f2bf(x0.x) | ((unsigned)f2bf(x0.y) << 16);
            p0.y = f2bf(x0.z) | ((unsigned)f2bf(x0.w) << 16);
            p0.z = f2bf(x1.x) | ((unsigned)f2bf(x1.y) << 16);
            p0.w = f2bf(x1.z) | ((unsigned)f2bf(x1.w) << 16);
            p1.x = f2bf(x2.x) | ((unsigned)f2bf(x2.y) << 16);
            p1.y = f2bf(x2.z) | ((unsigned)f2bf(x2.w) << 16);
            p1.z = f2bf(x3.x) | ((unsigned)f2bf(x3.y) << 16);
            p1.w = f2bf(x3.z) | ((unsigned)f2bf(x3.w) << 16);
            char* abase = (char*)Al + ag * 128;
            int sw = (ag & 7) << 4;
            *(uint4*)(abase + ((aseg * 32 + 0) ^ sw)) = p0;
            *(uint4*)(abase + ((aseg * 32 + 16) ^ sw)) = p1;
        }
        // stage B transposed: Bl[w][f] from T[f][w]
        {
            char* bb = (char*)Bl;
#pragma unroll
            for (int half = 0; half < 2; ++half) {
                int ff = bfr + half * 32;
                us8 tv = *(const us8*)(Tb + (size_t)(f0 + ff) * WW + W0 + bws * 8);
#pragma unroll
                for (int j = 0; j < 8; ++j) {
                    int wloc = bws * 8 + j;
                    *(unsigned short*)(bb + wloc * 128 + ((ff * 2) ^ (j << 4))) = tv[j];
                }
            }
        }
        __syncthreads();
#pragma unroll
        for (int kc = 0; kc < 2; ++kc) {
            bf16x8 af[2], bf[2];
#pragma unroll
            for (int i = 0; i < 2; ++i) {
                int gr = wr * 32 + i * 16 + lr;
                af[i] = *(const bf16x8*)((char*)Al + gr * 128 + ((kc * 64 + lg * 16) ^ ((gr & 7) << 4)));
                int wrow2 = wc * 32 + i * 16 + lr;
                bf[i] = *(const bf16x8*)((char*)Bl + wrow2 * 128 + ((kc * 64 + lg * 16) ^ ((wrow2 & 7) << 4)));
            }
#pragma unroll
            for (int i = 0; i < 2; ++i)
#pragma unroll
                for (int j = 0; j < 2; ++j)
                    acc[i][j] = mfma16(af[i], bf[j], acc[i][j]);
        }
        __syncthreads();
    }
#pragma unroll
    for (int i = 0; i < 2; ++i)
#pragma unroll
        for (int j = 0; j < 2; ++j)
#pragma unroll
            for (int r = 0; r < 4; ++r) {
                int g = G0 + wr * 32 + i * 16 + lg * 4 + r;
                int w = W0 + wc * 32 + j * 16 + lr;
                size_t o = ((size_t)bc * M + g) * WW + w;
                if (MODE == 0) ob[o] = f2bf(acc[i][j][r]);
                else of[o] += acc[i][j][r];
            }
}

// ---------------- fused attention: S=K.Q^T (mfma) -> qk out -> softmax -> PV (mfma) ----------------
// grid (BC*HH, 8 qtiles of 64). block 256 = 4 waves, each wave owns 16 q rows.
__global__ __launch_bounds__(256, 1) void attn_fused(
    const unsigned short* __restrict__ qb, const unsigned short* __restrict__ kb,
    const unsigned short* __restrict__ vb, float* __restrict__ qko,
    unsigned short* __restrict__ ab) {
    __shared__ unsigned short Kl[512 * 32];       // [kw][d]
    __shared__ unsigned short Vl[32 * 512];       // [d][kw] swizzled
    __shared__ unsigned short Ql[64 * 32];        // [q][d]
    __shared__ unsigned short SP[4][16 * 512];    // per-wave [q16][kw] swizzled
    const int bch = blockIdx.x, qt = blockIdx.y;
    const int bc = bch >> 3, h = bch & 7;
    const int tx = threadIdx.x;
    const int lane = tx & 63, wid = tx >> 6;
    const int lr = lane & 15, lg = lane >> 4;

    const unsigned short* kbase = kb + ((size_t)bc * FF + h * DH) * WW;
    const unsigned short* vbase = vb + ((size_t)bc * FF + h * DH) * WW;
    const unsigned short* qbase = qb + ((size_t)bc * FF + h * DH) * WW + qt * 64;

    // stage K transposed -> Kl[kw][d]
    {
        int d0 = ((tx >> 3) & 7) * 4;
#pragma unroll
        for (int rep = 0; rep < 2; ++rep) {
            int kw0 = (tx & 7) * 8 + ((tx >> 6) & 3) * 64 + rep * 256;
            us8 v0 = *(const us8*)(kbase + (size_t)(d0 + 0) * WW + kw0);
            us8 v1 = *(const us8*)(kbase + (size_t)(d0 + 1) * WW + kw0);
            us8 v2 = *(const us8*)(kbase + (size_t)(d0 + 2) * WW + kw0);
            us8 v3 = *(const us8*)(kbase + (size_t)(d0 + 3) * WW + kw0);
#pragma unroll
            for (int j = 0; j < 8; ++j) {
                us4 p; p.x = v0[j]; p.y = v1[j]; p.z = v2[j]; p.w = v3[j];
                *(us4*)(&Kl[(kw0 + j) * 32 + d0]) = p;
            }
        }
    }
    // stage V -> Vl[d][kw], swizzled
    {
        int d = tx >> 3;
        int sw = (d & 7) << 4;
#pragma unroll
        for (int rep = 0; rep < 8; ++rep) {
            int kw0 = (tx & 7) * 8 + rep * 64;
            us8 tv = *(const us8*)(vbase + (size_t)d * WW + kw0);
            *(us8*)((char*)Vl + d * 1024 + ((kw0 * 2) ^ sw)) = tv;
        }
    }
    // stage Q transposed -> Ql[q][d] (wave 0 only)
    if (tx < 64) {
        int d0 = ((tx >> 3) & 7) * 4;
        int q0 = (tx & 7) * 8;
        us8 v0 = *(const us8*)(qbase + (size_t)(d0 + 0) * WW + q0);
        us8 v1 = *(const us8*)(qbase + (size_t)(d0 + 1) * WW + q0);
        us8 v2 = *(const us8*)(qbase + (size_t)(d0 + 2) * WW + q0);
        us8 v3 = *(const us8*)(qbase + (size_t)(d0 + 3) * WW + q0);
#pragma unroll
        for (int j = 0; j < 8; ++j) {
            us4 p; p.x = v0[j]; p.y = v1[j]; p.z = v2[j]; p.w = v3[j];
            *(us4*)(&Ql[(q0 + j) * 32 + d0]) = p;
        }
    }
    __syncthreads();

    char* SPw = (char*)SP[wid];
    const int q0w = wid * 16;
    const int spsw = (lr & 7) << 4;

    bf16x8 qf = *(const bf16x8*)((char*)Ql + (q0w + lr) * 64 + lg * 16);
    f32x4 s[32];
#pragma unroll
    for (int i = 0; i < 32; ++i) s[i] = (f32x4){0.f, 0.f, 0.f, 0.f};
    // S^T[kw][q] = K[kw][d] . Q[q][d]^T
#pragma unroll
    for (int kwt = 0; kwt < 32; ++kwt) {
        bf16x8 kf = *(const bf16x8*)((char*)Kl + (kwt * 16 + lr) * 64 + lg * 16);
        s[kwt] = mfma16(kf, qf, s[kwt]);
    }
    // scale, stash bf16 S into SPw, row max
    float mx = -3.0e38f;
#pragma unroll
    for (int kwt = 0; kwt < 32; ++kwt) {
        s[kwt] *= 0.0625f;
        us4 p;
        p.x = f2bf(s[kwt][0]); p.y = f2bf(s[kwt][1]);
        p.z = f2bf(s[kwt][2]); p.w = f2bf(s[kwt][3]);
        *(us4*)(SPw + lr * 1024 + ((kwt * 32 + lg * 8) ^ spsw)) = p;
        mx = fmaxf(mx, fmaxf(fmaxf(s[kwt][0], s[kwt][1]), fmaxf(s[kwt][2], s[kwt][3])));
    }
    mx = fmaxf(mx, __shfl_xor(mx, 16));
    mx = fmaxf(mx, __shfl_xor(mx, 32));
    // coalesced qk store from SPw
    {
        size_t qrow = (size_t)bch * WW + qt * 64 + q0w;
#pragma unroll
        for (int r = 0; r < 16; ++r) {
            us8 row = *(const us8*)(SPw + r * 1024 + ((lane * 16) ^ ((r & 7) << 4)));
            float4 f0, f1;
            f0.x = bf2f(row[0]); f0.y = bf2f(row[1]); f0.z = bf2f(row[2]); f0.w = bf2f(row[3]);
            f1.x = bf2f(row[4]); f1.y = bf2f(row[5]); f1.z = bf2f(row[6]); f1.w = bf2f(row[7]);
            float* op = qko + (qrow + r) * WW + lane * 8;
            *(float4*)op = f0;
            *(float4*)(op + 4) = f1;
        }
    }
    // softmax: exp & sum (per q column = lane lr group)
    float sum = 0.f;
#pragma unroll
    for (int kwt = 0; kwt < 32; ++kwt) {
#pragma unroll
        for (int r = 0; r < 4; ++r) {
            float p = __expf(s[kwt][r] - mx);
            s[kwt][r] = p;
            sum += p;
        }
    }
    sum += __shfl_xor(sum, 16);
    sum += __shfl_xor(sum, 32);
    float inv = 1.0f / sum;
    // normalized P -> SPw (bf16)
#pragma unroll
    for (int kwt = 0; kwt < 32; ++kwt) {
        us4 p;
        p.x = f2bf(s[kwt][0] * inv); p.y = f2bf(s[kwt][1] * inv);
        p.z = f2bf(s[kwt][2] * inv); p.w = f2bf(s[kwt][3] * inv);
        *(us4*)(SPw + lr * 1024 + ((kwt * 32 + lg * 8) ^ spsw)) = p;
    }
    // PV: a^T[d][q] = V[d][kw] . P[q][kw]^T
    f32x4 av[2];
    av[0] = (f32x4){0.f, 0.f, 0.f, 0.f};
    av[1] = (f32x4){0.f, 0.f, 0.f, 0.f};
#pragma unroll
    for (int kc = 0; kc < 16; ++kc) {
        int kw0 = kc * 32;
        bf16x8 pf = *(const bf16x8*)(SPw + lr * 1024 + ((kw0 * 2 + lg * 16) ^ spsw));
#pragma unroll
        for (int di = 0; di < 2; ++di) {
            int vr = di * 16 + lr;
            bf16x8 vf = *(const bf16x8*)((char*)Vl + vr * 1024 + ((kw0 * 2 + lg * 16) ^ ((vr & 7) << 4)));
            av[di] = mfma16(vf, pf, av[di]);
        }
    }
    // store a^T (= [f][w] layout)
#pragma unroll
    for (int di = 0; di < 2; ++di)
#pragma unroll
        for (int r = 0; r < 4; ++r) {
            int d = h * DH + di * 16 + lg * 4 + r;
            ab[((size_t)bc * FF + d) * WW + qt * 64 + q0w + lr] = f2bf(av[di][r]);
        }
}

// ---------------- LDS-tiled depthwise 16-ch mix ----------------
// MODE 0: fo = x + mix (f32); MODE 1: bo = sqrelu(mix) (bf16)
template <int NPC, int MODE>
__global__ __launch_bounds__(256) void dwmix(
    const unsigned short* __restrict__ in, const float* __restrict__ wdw,
    const float* __restrict__ x, float* __restrict__ fo, unsigned short* __restrict__ bo) {
    __shared__ unsigned short L[16][1024];
    int b = blockIdx.y;
    size_t base = (size_t)blockIdx.x * 1024;
    int tx = threadIdx.x;
#pragma unroll
    for (int r = 0; r < 8; ++r) {
        int idx = tx + r * 256;
        int ci = idx >> 7;
        int seg = idx & 127;
        *(us8*)&L[ci][seg * 8] = *(const us8*)(in + ((size_t)(b * 16 + ci)) * NPC + base + seg * 8);
    }
    __syncthreads();
#pragma unroll
    for (int pos = 0; pos < 4; ++pos) {
        int fw = tx + pos * 256;
        float vin[16];
#pragma unroll
        for (int ci = 0; ci < 16; ++ci) vin[ci] = bf2f(L[ci][fw]);
#pragma unroll
        for (int o = 0; o < 16; ++o) {
            float s = 0.f;
#pragma unroll
            for (int ci = 0; ci < 16; ++ci) s += wdw[o * 16 + ci] * vin[ci];
            size_t oi = ((size_t)(b * 16 + o)) * NPC + base + fw;
            if (MODE == 0) fo[oi] = x[oi] + s;
            else { s = fmaxf(s, 0.f); bo[oi] = f2bf(s * s); }
        }
    }
}

extern "C" void kernel_launch(void* const* d_in, const int* in_sizes, int n_in,
                              void* d_out, int out_size, void* d_ws, size_t ws_size,
                              hipStream_t stream) {
    const float* x      = (const float*)d_in[0];
    const float* conv_q = (const float*)d_in[1];
    const float* conv_k = (const float*)d_in[2];
    const float* conv_v = (const float*)d_in[3];
    const float* wq     = (const float*)d_in[4];
    const float* wk     = (const float*)d_in[5];
    const float* wv     = (const float*)d_in[6];
    const float* wo_pw  = (const float*)d_in[7];
    const float* wo_dw  = (const float*)d_in[8];
    const float* g1     = (const float*)d_in[9];
    const float* b1     = (const float*)d_in[10];
    const float* g2     = (const float*)d_in[11];
    const float* b2     = (const float*)d_in[12];
    const float* w1_pw  = (const float*)d_in[13];
    const float* w1_dw  = (const float*)d_in[14];
    const float* w2_pw  = (const float*)d_in[15];

    float* hout  = (float*)d_out;
    float* qkout = (float*)d_out + 4194304;

    char* ws = (char*)d_ws;
    const size_t MB8 = (size_t)8 << 20;
    unsigned short* n1 = (unsigned short*)(ws + 0 * MB8);   // later: ab
    unsigned short* cq = (unsigned short*)(ws + 1 * MB8);   // later: pwb
    unsigned short* ck = (unsigned short*)(ws + 2 * MB8);   // later: n2
    unsigned short* cv = (unsigned short*)(ws + 3 * MB8);
    unsigned short* qb = (unsigned short*)(ws + 4 * MB8);
    unsigned short* kb = (unsigned short*)(ws + 5 * MB8);
    unsigned short* vb = (unsigned short*)(ws + 6 * MB8);
    unsigned short* u1 = (unsigned short*)(ws + 3 * MB8);   // 32 MB, aliases cv/qb/kb/vb (dead)
    unsigned short* u2 = (unsigned short*)(ws + 7 * MB8);   // 32 MB
    unsigned short* ab  = n1;
    unsigned short* pwb = cq;
    unsigned short* n2  = ck;

    ln_kernel<<<dim3(BC, 2), 256, 0, stream>>>(x, g1, b1, n1);
    conv3_kernel<<<dim3(BC, FF, 2), 256, 0, stream>>>(n1, conv_q, conv_k, conv_v, cq, ck, cv);
    mgemm<256, 256, 0><<<dim3(BC, 4, 8), 256, 0, stream>>>(cq, wq, qb, nullptr);
    mgemm<256, 256, 0><<<dim3(BC, 4, 8), 256, 0, stream>>>(ck, wk, kb, nullptr);
    mgemm<256, 256, 0><<<dim3(BC, 4, 8), 256, 0, stream>>>(cv, wv, vb, nullptr);
    attn_fused<<<dim3(BC * HH, 8), 256, 0, stream>>>(qb, kb, vb, qkout, ab);
    mgemm<256, 256, 0><<<dim3(BC, 4, 8), 256, 0, stream>>>(ab, wo_pw, pwb, nullptr);
    dwmix<131072, 0><<<dim3(128, BB), 256, 0, stream>>>(pwb, wo_dw, x, hout, nullptr);
    ln_kernel<<<dim3(BC, 2), 256, 0, stream>>>(hout, g2, b2, n2);
    mgemm<256, 1024, 0><<<dim3(BC, 16, 8), 256, 0, stream>>>(n2, w1_pw, u1, nullptr);
    dwmix<524288, 1><<<dim3(512, BB), 256, 0, stream>>>(u1, w1_dw, nullptr, nullptr, u2);
    mgemm<1024, 256, 1><<<dim3(BC, 4, 8), 256, 0, stream>>>(u2, w2_pw, nullptr, hout);
}

// Round 3
// 391.457 us; speedup vs baseline: 3.3779x; 1.6119x over previous
//
#include <hip/hip_runtime.h>

#define BB 2
#define CC 16
#define BC 32
#define FF 256
#define WW 512
#define HH 8
#define DH 32

using bf16x8 = __attribute__((ext_vector_type(8))) __bf16;
using f32x4  = __attribute__((ext_vector_type(4))) float;
using us8    = __attribute__((ext_vector_type(8))) unsigned short;
using us4    = __attribute__((ext_vector_type(4))) unsigned short;

__device__ __forceinline__ float bf2f(unsigned short u) {
    union { unsigned int i; float f; } x; x.i = ((unsigned int)u) << 16; return x.f;
}
__device__ __forceinline__ unsigned short f2bf(float f) {
    union { float f; unsigned int i; } x; x.f = f;
    unsigned int r = x.i + 0x7fffu + ((x.i >> 16) & 1u);   // round-nearest-even
    return (unsigned short)(r >> 16);
}
__device__ __forceinline__ f32x4 mfma16(bf16x8 a, bf16x8 b, f32x4 c) {
    return __builtin_amdgcn_mfma_f32_16x16x32_bf16(a, b, c, 0, 0, 0);
}

// ---------------- LayerNorm over f (axis stride W) ----------------
__global__ __launch_bounds__(256) void ln_kernel(
    const float* __restrict__ x, const float* __restrict__ g,
    const float* __restrict__ bta, unsigned short* __restrict__ out) {
    int bc = blockIdx.x;
    int c = bc & (CC - 1);
    int w = blockIdx.y * 256 + threadIdx.x;
    const float* xp = x + ((size_t)bc * FF) * WW + w;
    float s = 0.f, s2 = 0.f;
#pragma unroll 4
    for (int f = 0; f < FF; ++f) { float t = xp[(size_t)f * WW]; s += t; s2 += t * t; }
    float m = s * (1.f / FF);
    float v = s2 * (1.f / FF) - m * m;
    float r = rsqrtf(v + 1e-5f);
    unsigned short* op = out + ((size_t)bc * FF) * WW + w;
    const float* gp = g + c * FF;
    const float* bp = bta + c * FF;
#pragma unroll 4
    for (int f = 0; f < FF; ++f) {
        float t = (xp[(size_t)f * WW] - m) * r * gp[f] + bp[f];
        op[(size_t)f * WW] = f2bf(t);
    }
}

// ---------------- conv weight repack: Aw[tensor][kstep5][co16][k32] bf16 ----------------
// k<16: tap=2*kstep, ci=k ; k>=16: tap=2*kstep+1, ci=k-16 ; tap 9 -> 0
__global__ __launch_bounds__(256) void wrepack(
    const float* __restrict__ wq, const float* __restrict__ wk, const float* __restrict__ wv,
    unsigned short* __restrict__ Aw) {
    int idx = blockIdx.x * 256 + threadIdx.x;   // < 3*2560
    int tensor = idx / 2560;
    int r = idx - tensor * 2560;
    int tp = r >> 9, co = (r >> 5) & 15, k = r & 31;
    int tap = tp * 2 + (k >> 4), ci = k & 15;
    float v = 0.f;
    if (tap < 9) {
        const float* w = tensor == 0 ? wq : (tensor == 1 ? wk : wv);
        v = w[(co * 16 + ci) * 9 + tap];
    }
    Aw[idx] = f2bf(v);
}

// ---------------- MFMA conv3x3: tap-decomposed implicit GEMM ----------------
// block tile: f x w = 4 x 64 (wave wid owns f-row wid, 4 pixel-16-subtiles)
// LDS X: [6 f][68 w][16 ci] bf16 (zero halo). B frag = ds_read_b128.
__global__ __launch_bounds__(256) void conv3_mfma(
    const unsigned short* __restrict__ n1, const unsigned short* __restrict__ Aw,
    unsigned short* __restrict__ oq, unsigned short* __restrict__ ok,
    unsigned short* __restrict__ ov) {
    __shared__ __align__(16) unsigned short Xl[6][68][16];
    const int b = blockIdx.z;
    const int f0 = blockIdx.y * 4;
    const int w0 = blockIdx.x * 64;
    const int tx = threadIdx.x;
    const int lane = tx & 63, wid = tx >> 6;
    const int lr = lane & 15, lg = lane >> 4;

    // zero fill
    {
        uint4 z{0, 0, 0, 0};
        for (int i = tx; i < 816; i += 256) ((uint4*)Xl)[i] = z;
    }
    __syncthreads();
    // stage interior (transpose [ci][f][w] -> [f][w][ci])
    for (int task = tx; task < 960; task += 256) {
        int c = task % 10;
        int fr = (task / 10) % 6;
        int ci = task / 60;
        int fy = f0 - 1 + fr;
        int wx = w0 - 8 + c * 8;
        if (fy >= 0 && fy < FF && wx >= 0 && wx <= WW - 8) {
            us8 v = *(const us8*)(n1 + ((size_t)(b * CC + ci) * FF + fy) * WW + wx);
#pragma unroll
            for (int e = 0; e < 8; ++e) {
                int wl = c * 8 + e - 7;
                if (wl >= 0 && wl < 66) Xl[fr][wl][ci] = v[e];
            }
        }
    }
    __syncthreads();

    // A fragments: 3 tensors x 5 ksteps, each lane 16B
    bf16x8 A[3][5];
#pragma unroll
    for (int t3 = 0; t3 < 3; ++t3)
#pragma unroll
        for (int t = 0; t < 5; ++t)
            A[t3][t] = *(const bf16x8*)(Aw + ((t3 * 5 + t) * 16 + lr) * 32 + lg * 8);

    // per-lane tap offsets (bytes) for its K-half
    const bool h = (lane & 32) != 0;
    // half0 taps {0,2,4,6,8}; half1 taps {1,3,5,7, dummy(=tap8 addr, zero A)}
    int doff[5];
    doff[0] = (h ? (-68 * 32) : ((-68 - 1) * 32));
    doff[1] = (h ? (-1 * 32) : ((-68 + 1) * 32));
    doff[2] = (h ? (1 * 32) : 0);
    doff[3] = (h ? (68 * 32) : ((68 - 1) * 32));
    doff[4] = ((68 + 1) * 32);

    const int fl = wid + 1;
    const int fglob = f0 + wid;
    char* xbase = (char*)Xl + (fl * 68 + 1) * 32 + ((lg & 1) ? 16 : 0);

#pragma unroll
    for (int pt = 0; pt < 4; ++pt) {
        char* bb = xbase + (pt * 16 + lr) * 32;
        bf16x8 Bf[5];
#pragma unroll
        for (int t = 0; t < 5; ++t) Bf[t] = *(const bf16x8*)(bb + doff[t]);
        f32x4 aq = {0.f, 0.f, 0.f, 0.f}, ak = {0.f, 0.f, 0.f, 0.f}, av = {0.f, 0.f, 0.f, 0.f};
#pragma unroll
        for (int t = 0; t < 5; ++t) {
            aq = mfma16(A[0][t], Bf[t], aq);
            ak = mfma16(A[1][t], Bf[t], ak);
            av = mfma16(A[2][t], Bf[t], av);
        }
        int w = w0 + pt * 16 + lr;
#pragma unroll
        for (int r = 0; r < 4; ++r) {
            int co = lg * 4 + r;
            size_t o = ((size_t)(b * CC + co) * FF + fglob) * WW + w;
            oq[o] = f2bf(aq[r]);
            ok[o] = f2bf(ak[r]);
            ov[o] = f2bf(av[r]);
        }
    }
}

// ---------------- MFMA per-channel GEMM ----------------
template <int K, int M, int MODE>
__global__ __launch_bounds__(256, 4) void mgemm(
    const unsigned short* __restrict__ T, const float* __restrict__ Wt,
    unsigned short* __restrict__ ob, float* __restrict__ of) {
    __shared__ unsigned short Al[64 * 64];
    __shared__ unsigned short Bl[64 * 64];
    const int bc = blockIdx.x, c = bc & 15;
    const int G0 = blockIdx.y * 64, W0 = blockIdx.z * 64;
    const int tx = threadIdx.x;
    const int lane = tx & 63, wid = tx >> 6;
    const int lr = lane & 15, lg = lane >> 4;
    const int wr = wid >> 1, wc = wid & 1;

    const unsigned short* Tb = T + (size_t)bc * K * WW;
    const float* Wb = Wt + ((size_t)c * M + G0) * K;

    f32x4 acc[2][2];
#pragma unroll
    for (int i = 0; i < 2; ++i)
#pragma unroll
        for (int j = 0; j < 2; ++j) acc[i][j] = (f32x4){0.f, 0.f, 0.f, 0.f};

    const int ag = tx >> 2, aseg = tx & 3;
    const int bfr = tx >> 3, bws = tx & 7;

    for (int f0 = 0; f0 < K; f0 += 64) {
        {
            const float* wrow = Wb + (size_t)ag * K + f0 + aseg * 16;
            float4 x0 = *(const float4*)(wrow + 0);
            float4 x1 = *(const float4*)(wrow + 4);
            float4 x2 = *(const float4*)(wrow + 8);
            float4 x3 = *(const float4*)(wrow + 12);
            uint4 p0, p1;
            p0.x = f2bf(x0.x) | ((unsigned)f2bf(x0.y) << 16);
            p0.y = f2bf(x0.z) | ((unsigned)f2bf(x0.w) << 16);
            p0.z = f2bf(x1.x) | ((unsigned)f2bf(x1.y) << 16);
            p0.w = f2bf(x1.z) | ((unsigned)f2bf(x1.w) << 16);
            p1.x = f2bf(x2.x) | ((unsigned)f2bf(x2.y) << 16);
            p1.y = f2bf(x2.z) | ((unsigned)f2bf(x2.w) << 16);
            p1.z = f2bf(x3.x) | ((unsigned)f2bf(x3.y) << 16);
            p1.w = f2bf(x3.z) | ((unsigned)f2bf(x3.w) << 16);
            char* abase = (char*)Al + ag * 128;
            int sw = (ag & 7) << 4;
            *(uint4*)(abase + ((aseg * 32 + 0) ^ sw)) = p0;
            *(uint4*)(abase + ((aseg * 32 + 16) ^ sw)) = p1;
        }
        {
            char* bb = (char*)Bl;
#pragma unroll
            for (int half = 0; half < 2; ++half) {
                int ff = bfr + half * 32;
                us8 tv = *(const us8*)(Tb + (size_t)(f0 + ff) * WW + W0 + bws * 8);
#pragma unroll
                for (int j = 0; j < 8; ++j) {
                    int wloc = bws * 8 + j;
                    *(unsigned short*)(bb + wloc * 128 + ((ff * 2) ^ (j << 4))) = tv[j];
                }
            }
        }
        __syncthreads();
#pragma unroll
        for (int kc = 0; kc < 2; ++kc) {
            bf16x8 af[2], bf[2];
#pragma unroll
            for (int i = 0; i < 2; ++i) {
                int gr = wr * 32 + i * 16 + lr;
                af[i] = *(const bf16x8*)((char*)Al + gr * 128 + ((kc * 64 + lg * 16) ^ ((gr & 7) << 4)));
                int wrow2 = wc * 32 + i * 16 + lr;
                bf[i] = *(const bf16x8*)((char*)Bl + wrow2 * 128 + ((kc * 64 + lg * 16) ^ ((wrow2 & 7) << 4)));
            }
#pragma unroll
            for (int i = 0; i < 2; ++i)
#pragma unroll
                for (int j = 0; j < 2; ++j)
                    acc[i][j] = mfma16(af[i], bf[j], acc[i][j]);
        }
        __syncthreads();
    }
#pragma unroll
    for (int i = 0; i < 2; ++i)
#pragma unroll
        for (int j = 0; j < 2; ++j)
#pragma unroll
            for (int r = 0; r < 4; ++r) {
                int g = G0 + wr * 32 + i * 16 + lg * 4 + r;
                int w = W0 + wc * 32 + j * 16 + lr;
                size_t o = ((size_t)bc * M + g) * WW + w;
                if (MODE == 0) ob[o] = f2bf(acc[i][j][r]);
                else of[o] += acc[i][j][r];
            }
}

// ---------------- fused attention ----------------
__global__ __launch_bounds__(256, 1) void attn_fused(
    const unsigned short* __restrict__ qb, const unsigned short* __restrict__ kb,
    const unsigned short* __restrict__ vb, float* __restrict__ qko,
    unsigned short* __restrict__ ab) {
    __shared__ unsigned short Kl[512 * 32];
    __shared__ unsigned short Vl[32 * 512];
    __shared__ unsigned short Ql[64 * 32];
    __shared__ unsigned short SP[4][16 * 512];
    const int bch = blockIdx.x, qt = blockIdx.y;
    const int bc = bch >> 3, h = bch & 7;
    const int tx = threadIdx.x;
    const int lane = tx & 63, wid = tx >> 6;
    const int lr = lane & 15, lg = lane >> 4;

    const unsigned short* kbase = kb + ((size_t)bc * FF + h * DH) * WW;
    const unsigned short* vbase = vb + ((size_t)bc * FF + h * DH) * WW;
    const unsigned short* qbase = qb + ((size_t)bc * FF + h * DH) * WW + qt * 64;

    {
        int d0 = ((tx >> 3) & 7) * 4;
#pragma unroll
        for (int rep = 0; rep < 2; ++rep) {
            int kw0 = (tx & 7) * 8 + ((tx >> 6) & 3) * 64 + rep * 256;
            us8 v0 = *(const us8*)(kbase + (size_t)(d0 + 0) * WW + kw0);
            us8 v1 = *(const us8*)(kbase + (size_t)(d0 + 1) * WW + kw0);
            us8 v2 = *(const us8*)(kbase + (size_t)(d0 + 2) * WW + kw0);
            us8 v3 = *(const us8*)(kbase + (size_t)(d0 + 3) * WW + kw0);
#pragma unroll
            for (int j = 0; j < 8; ++j) {
                us4 p; p.x = v0[j]; p.y = v1[j]; p.z = v2[j]; p.w = v3[j];
                *(us4*)(&Kl[(kw0 + j) * 32 + d0]) = p;
            }
        }
    }
    {
        int d = tx >> 3;
        int sw = (d & 7) << 4;
#pragma unroll
        for (int rep = 0; rep < 8; ++rep) {
            int kw0 = (tx & 7) * 8 + rep * 64;
            us8 tv = *(const us8*)(vbase + (size_t)d * WW + kw0);
            *(us8*)((char*)Vl + d * 1024 + ((kw0 * 2) ^ sw)) = tv;
        }
    }
    if (tx < 64) {
        int d0 = ((tx >> 3) & 7) * 4;
        int q0 = (tx & 7) * 8;
        us8 v0 = *(const us8*)(qbase + (size_t)(d0 + 0) * WW + q0);
        us8 v1 = *(const us8*)(qbase + (size_t)(d0 + 1) * WW + q0);
        us8 v2 = *(const us8*)(qbase + (size_t)(d0 + 2) * WW + q0);
        us8 v3 = *(const us8*)(qbase + (size_t)(d0 + 3) * WW + q0);
#pragma unroll
        for (int j = 0; j < 8; ++j) {
            us4 p; p.x = v0[j]; p.y = v1[j]; p.z = v2[j]; p.w = v3[j];
            *(us4*)(&Ql[(q0 + j) * 32 + d0]) = p;
        }
    }
    __syncthreads();

    char* SPw = (char*)SP[wid];
    const int q0w = wid * 16;
    const int spsw = (lr & 7) << 4;

    bf16x8 qf = *(const bf16x8*)((char*)Ql + (q0w + lr) * 64 + lg * 16);
    f32x4 s[32];
#pragma unroll
    for (int i = 0; i < 32; ++i) s[i] = (f32x4){0.f, 0.f, 0.f, 0.f};
#pragma unroll
    for (int kwt = 0; kwt < 32; ++kwt) {
        bf16x8 kf = *(const bf16x8*)((char*)Kl + (kwt * 16 + lr) * 64 + lg * 16);
        s[kwt] = mfma16(kf, qf, s[kwt]);
    }
    float mx = -3.0e38f;
#pragma unroll
    for (int kwt = 0; kwt < 32; ++kwt) {
        s[kwt] *= 0.0625f;
        us4 p;
        p.x = f2bf(s[kwt][0]); p.y = f2bf(s[kwt][1]);
        p.z = f2bf(s[kwt][2]); p.w = f2bf(s[kwt][3]);
        *(us4*)(SPw + lr * 1024 + ((kwt * 32 + lg * 8) ^ spsw)) = p;
        mx = fmaxf(mx, fmaxf(fmaxf(s[kwt][0], s[kwt][1]), fmaxf(s[kwt][2], s[kwt][3])));
    }
    mx = fmaxf(mx, __shfl_xor(mx, 16));
    mx = fmaxf(mx, __shfl_xor(mx, 32));
    {
        size_t qrow = (size_t)bch * WW + qt * 64 + q0w;
#pragma unroll
        for (int r = 0; r < 16; ++r) {
            us8 row = *(const us8*)(SPw + r * 1024 + ((lane * 16) ^ ((r & 7) << 4)));
            float4 f0, f1;
            f0.x = bf2f(row[0]); f0.y = bf2f(row[1]); f0.z = bf2f(row[2]); f0.w = bf2f(row[3]);
            f1.x = bf2f(row[4]); f1.y = bf2f(row[5]); f1.z = bf2f(row[6]); f1.w = bf2f(row[7]);
            float* op = qko + (qrow + r) * WW + lane * 8;
            *(float4*)op = f0;
            *(float4*)(op + 4) = f1;
        }
    }
    float sum = 0.f;
#pragma unroll
    for (int kwt = 0; kwt < 32; ++kwt) {
#pragma unroll
        for (int r = 0; r < 4; ++r) {
            float p = __expf(s[kwt][r] - mx);
            s[kwt][r] = p;
            sum += p;
        }
    }
    sum += __shfl_xor(sum, 16);
    sum += __shfl_xor(sum, 32);
    float inv = 1.0f / sum;
#pragma unroll
    for (int kwt = 0; kwt < 32; ++kwt) {
        us4 p;
        p.x = f2bf(s[kwt][0] * inv); p.y = f2bf(s[kwt][1] * inv);
        p.z = f2bf(s[kwt][2] * inv); p.w = f2bf(s[kwt][3] * inv);
        *(us4*)(SPw + lr * 1024 + ((kwt * 32 + lg * 8) ^ spsw)) = p;
    }
    f32x4 av[2];
    av[0] = (f32x4){0.f, 0.f, 0.f, 0.f};
    av[1] = (f32x4){0.f, 0.f, 0.f, 0.f};
#pragma unroll
    for (int kc = 0; kc < 16; ++kc) {
        int kw0 = kc * 32;
        bf16x8 pf = *(const bf16x8*)(SPw + lr * 1024 + ((kw0 * 2 + lg * 16) ^ spsw));
#pragma unroll
        for (int di = 0; di < 2; ++di) {
            int vr = di * 16 + lr;
            bf16x8 vf = *(const bf16x8*)((char*)Vl + vr * 1024 + ((kw0 * 2 + lg * 16) ^ ((vr & 7) << 4)));
            av[di] = mfma16(vf, pf, av[di]);
        }
    }
#pragma unroll
    for (int di = 0; di < 2; ++di)
#pragma unroll
        for (int r = 0; r < 4; ++r) {
            int d = h * DH + di * 16 + lg * 4 + r;
            ab[((size_t)bc * FF + d) * WW + qt * 64 + q0w + lr] = f2bf(av[di][r]);
        }
}

// ---------------- LDS-tiled depthwise 16-ch mix ----------------
template <int NPC, int MODE>
__global__ __launch_bounds__(256) void dwmix(
    const unsigned short* __restrict__ in, const float* __restrict__ wdw,
    const float* __restrict__ x, float* __restrict__ fo, unsigned short* __restrict__ bo) {
    __shared__ unsigned short L[16][1024];
    int b = blockIdx.y;
    size_t base = (size_t)blockIdx.x * 1024;
    int tx = threadIdx.x;
#pragma unroll
    for (int r = 0; r < 8; ++r) {
        int idx = tx + r * 256;
        int ci = idx >> 7;
        int seg = idx & 127;
        *(us8*)&L[ci][seg * 8] = *(const us8*)(in + ((size_t)(b * 16 + ci)) * NPC + base + seg * 8);
    }
    __syncthreads();
#pragma unroll
    for (int pos = 0; pos < 4; ++pos) {
        int fw = tx + pos * 256;
        float vin[16];
#pragma unroll
        for (int ci = 0; ci < 16; ++ci) vin[ci] = bf2f(L[ci][fw]);
#pragma unroll
        for (int o = 0; o < 16; ++o) {
            float s = 0.f;
#pragma unroll
            for (int ci = 0; ci < 16; ++ci) s += wdw[o * 16 + ci] * vin[ci];
            size_t oi = ((size_t)(b * 16 + o)) * NPC + base + fw;
            if (MODE == 0) fo[oi] = x[oi] + s;
            else { s = fmaxf(s, 0.f); bo[oi] = f2bf(s * s); }
        }
    }
}

extern "C" void kernel_launch(void* const* d_in, const int* in_sizes, int n_in,
                              void* d_out, int out_size, void* d_ws, size_t ws_size,
                              hipStream_t stream) {
    const float* x      = (const float*)d_in[0];
    const float* conv_q = (const float*)d_in[1];
    const float* conv_k = (const float*)d_in[2];
    const float* conv_v = (const float*)d_in[3];
    const float* wq     = (const float*)d_in[4];
    const float* wk     = (const float*)d_in[5];
    const float* wv     = (const float*)d_in[6];
    const float* wo_pw  = (const float*)d_in[7];
    const float* wo_dw  = (const float*)d_in[8];
    const float* g1     = (const float*)d_in[9];
    const float* b1     = (const float*)d_in[10];
    const float* g2     = (const float*)d_in[11];
    const float* b2     = (const float*)d_in[12];
    const float* w1_pw  = (const float*)d_in[13];
    const float* w1_dw  = (const float*)d_in[14];
    const float* w2_pw  = (const float*)d_in[15];

    float* hout  = (float*)d_out;
    float* qkout = (float*)d_out + 4194304;

    char* ws = (char*)d_ws;
    const size_t MB8 = (size_t)8 << 20;
    unsigned short* n1 = (unsigned short*)(ws + 0 * MB8);   // later: ab
    unsigned short* cq = (unsigned short*)(ws + 1 * MB8);   // later: pwb
    unsigned short* ck = (unsigned short*)(ws + 2 * MB8);   // later: n2
    unsigned short* cv = (unsigned short*)(ws + 3 * MB8);
    unsigned short* qb = (unsigned short*)(ws + 4 * MB8);
    unsigned short* kb = (unsigned short*)(ws + 5 * MB8);
    unsigned short* vb = (unsigned short*)(ws + 6 * MB8);
    unsigned short* u1 = (unsigned short*)(ws + 3 * MB8);   // 32 MB aliases cv/qb/kb/vb (dead)
    unsigned short* u2 = (unsigned short*)(ws + 7 * MB8);   // 32 MB
    unsigned short* Awb = (unsigned short*)(ws + 7 * MB8);  // 15 KB, dead before u2 written
    unsigned short* ab  = n1;
    unsigned short* pwb = cq;
    unsigned short* n2  = ck;

    ln_kernel<<<dim3(BC, 2), 256, 0, stream>>>(x, g1, b1, n1);
    wrepack<<<dim3(30), 256, 0, stream>>>(wq + 0, wk + 0, wv + 0, Awb);
    // NOTE: wrepack consumes conv_q/conv_k/conv_v (3x3 kernels), not wq/wk/wv:
    wrepack<<<dim3(30), 256, 0, stream>>>(conv_q, conv_k, conv_v, Awb);
    conv3_mfma<<<dim3(8, 64, BB), 256, 0, stream>>>(n1, Awb, cq, ck, cv);
    mgemm<256, 256, 0><<<dim3(BC, 4, 8), 256, 0, stream>>>(cq, wq, qb, nullptr);
    mgemm<256, 256, 0><<<dim3(BC, 4, 8), 256, 0, stream>>>(ck, wk, kb, nullptr);
    mgemm<256, 256, 0><<<dim3(BC, 4, 8), 256, 0, stream>>>(cv, wv, vb, nullptr);
    attn_fused<<<dim3(BC * HH, 8), 256, 0, stream>>>(qb, kb, vb, qkout, ab);
    mgemm<256, 256, 0><<<dim3(BC, 4, 8), 256, 0, stream>>>(ab, wo_pw, pwb, nullptr);
    dwmix<131072, 0><<<dim3(128, BB), 256, 0, stream>>>(pwb, wo_dw, x, hout, nullptr);
    ln_kernel<<<dim3(BC, 2), 256, 0, stream>>>(hout, g2, b2, n2);
    mgemm<256, 1024, 0><<<dim3(BC, 16, 8), 256, 0, stream>>>(n2, w1_pw, u1, nullptr);
    dwmix<524288, 1><<<dim3(512, BB), 256, 0, stream>>>(u1, w1_dw, nullptr, nullptr, u2);
    mgemm<1024, 256, 1><<<dim3(BC, 4, 8), 256, 0, stream>>>(u2, w2_pw, nullptr, hout);
}

// Round 5
// 350.088 us; speedup vs baseline: 3.7771x; 1.1182x over previous
//
#include <hip/hip_runtime.h>

#define BB 2
#define CC 16
#define BC 32
#define FF 256
#define WW 512
#define HH 8
#define DH 32

using bf16x8 = __attribute__((ext_vector_type(8))) __bf16;
using f32x4  = __attribute__((ext_vector_type(4))) float;
using us8    = __attribute__((ext_vector_type(8))) unsigned short;
using us4    = __attribute__((ext_vector_type(4))) unsigned short;

__device__ __forceinline__ float bf2f(unsigned short u) {
    union { unsigned int i; float f; } x; x.i = ((unsigned int)u) << 16; return x.f;
}
__device__ __forceinline__ unsigned short f2bf(float f) {
    union { float f; unsigned int i; } x; x.f = f;
    unsigned int r = x.i + 0x7fffu + ((x.i >> 16) & 1u);   // round-nearest-even
    return (unsigned short)(r >> 16);
}
__device__ __forceinline__ f32x4 mfma16(bf16x8 a, bf16x8 b, f32x4 c) {
    return __builtin_amdgcn_mfma_f32_16x16x32_bf16(a, b, c, 0, 0, 0);
}

// ---------------- LayerNorm over f -> [f][w] bf16 ----------------
__global__ __launch_bounds__(256) void ln_kernel(
    const float* __restrict__ x, const float* __restrict__ g,
    const float* __restrict__ bta, unsigned short* __restrict__ out) {
    int bc = blockIdx.x;
    int c = bc & (CC - 1);
    int w = blockIdx.y * 256 + threadIdx.x;
    const float* xp = x + ((size_t)bc * FF) * WW + w;
    float s = 0.f, s2 = 0.f;
#pragma unroll 4
    for (int f = 0; f < FF; ++f) { float t = xp[(size_t)f * WW]; s += t; s2 += t * t; }
    float m = s * (1.f / FF);
    float v = s2 * (1.f / FF) - m * m;
    float r = rsqrtf(v + 1e-5f);
    unsigned short* op = out + ((size_t)bc * FF) * WW + w;
    const float* gp = g + c * FF;
    const float* bp = bta + c * FF;
#pragma unroll 4
    for (int f = 0; f < FF; ++f) {
        float t = (xp[(size_t)f * WW] - m) * r * gp[f] + bp[f];
        op[(size_t)f * WW] = f2bf(t);
    }
}

// ---------------- LayerNorm over f -> TRANSPOSED [w][f] bf16 ----------------
__global__ __launch_bounds__(256) void ln_t_kernel(
    const float* __restrict__ x, const float* __restrict__ g,
    const float* __restrict__ bta, unsigned short* __restrict__ out) {
    int bc = blockIdx.x;
    int c = bc & (CC - 1);
    int w = blockIdx.y * 256 + threadIdx.x;
    const float* xp = x + ((size_t)bc * FF) * WW + w;
    float s = 0.f, s2 = 0.f;
#pragma unroll 4
    for (int f = 0; f < FF; ++f) { float t = xp[(size_t)f * WW]; s += t; s2 += t * t; }
    float m = s * (1.f / FF);
    float v = s2 * (1.f / FF) - m * m;
    float r = rsqrtf(v + 1e-5f);
    unsigned short* op = out + ((size_t)bc * WW + w) * FF;
    const float* gp = g + c * FF;
    const float* bp = bta + c * FF;
    for (int f8 = 0; f8 < FF / 8; ++f8) {
        us8 pk;
#pragma unroll
        for (int e = 0; e < 8; ++e) {
            int f = f8 * 8 + e;
            float t = (xp[(size_t)f * WW] - m) * r * gp[f] + bp[f];
            pk[e] = f2bf(t);
        }
        *(us8*)(op + f8 * 8) = pk;
    }
}

// ---------------- conv weight repack ----------------
__global__ __launch_bounds__(256) void wrepack(
    const float* __restrict__ wq, const float* __restrict__ wk, const float* __restrict__ wv,
    unsigned short* __restrict__ Aw) {
    int idx = blockIdx.x * 256 + threadIdx.x;   // < 3*2560
    int tensor = idx / 2560;
    int r = idx - tensor * 2560;
    int tp = r >> 9, co = (r >> 5) & 15, k = r & 31;
    int tap = tp * 2 + (k >> 4), ci = k & 15;
    float v = 0.f;
    if (tap < 9) {
        const float* w = tensor == 0 ? wq : (tensor == 1 ? wk : wv);
        v = w[(co * 16 + ci) * 9 + tap];
    }
    Aw[idx] = f2bf(v);
}

// ---------------- MFMA conv3x3 ----------------
__global__ __launch_bounds__(256) void conv3_mfma(
    const unsigned short* __restrict__ n1, const unsigned short* __restrict__ Aw,
    unsigned short* __restrict__ oq, unsigned short* __restrict__ ok,
    unsigned short* __restrict__ ov) {
    __shared__ __align__(16) unsigned short Xl[6][68][16];
    const int b = blockIdx.z;
    const int f0 = blockIdx.y * 4;
    const int w0 = blockIdx.x * 64;
    const int tx = threadIdx.x;
    const int lane = tx & 63, wid = tx >> 6;
    const int lr = lane & 15, lg = lane >> 4;
    {
        uint4 z{0, 0, 0, 0};
        for (int i = tx; i < 816; i += 256) ((uint4*)Xl)[i] = z;
    }
    __syncthreads();
    for (int task = tx; task < 960; task += 256) {
        int c = task % 10;
        int fr = (task / 10) % 6;
        int ci = task / 60;
        int fy = f0 - 1 + fr;
        int wx = w0 - 8 + c * 8;
        if (fy >= 0 && fy < FF && wx >= 0 && wx <= WW - 8) {
            us8 v = *(const us8*)(n1 + ((size_t)(b * CC + ci) * FF + fy) * WW + wx);
#pragma unroll
            for (int e = 0; e < 8; ++e) {
                int wl = c * 8 + e - 7;
                if (wl >= 0 && wl < 66) Xl[fr][wl][ci] = v[e];
            }
        }
    }
    __syncthreads();
    bf16x8 A[3][5];
#pragma unroll
    for (int t3 = 0; t3 < 3; ++t3)
#pragma unroll
        for (int t = 0; t < 5; ++t)
            A[t3][t] = *(const bf16x8*)(Aw + ((t3 * 5 + t) * 16 + lr) * 32 + lg * 8);
    const bool h = (lane & 32) != 0;
    int doff[5];
    doff[0] = (h ? (-68 * 32) : ((-68 - 1) * 32));
    doff[1] = (h ? (-1 * 32) : ((-68 + 1) * 32));
    doff[2] = (h ? (1 * 32) : 0);
    doff[3] = (h ? (68 * 32) : ((68 - 1) * 32));
    doff[4] = ((68 + 1) * 32);
    const int fl = wid + 1;
    const int fglob = f0 + wid;
    char* xbase = (char*)Xl + (fl * 68 + 1) * 32 + ((lg & 1) ? 16 : 0);
#pragma unroll
    for (int pt = 0; pt < 4; ++pt) {
        char* bb = xbase + (pt * 16 + lr) * 32;
        bf16x8 Bf[5];
#pragma unroll
        for (int t = 0; t < 5; ++t) Bf[t] = *(const bf16x8*)(bb + doff[t]);
        f32x4 aq = {0.f, 0.f, 0.f, 0.f}, ak = {0.f, 0.f, 0.f, 0.f}, av = {0.f, 0.f, 0.f, 0.f};
#pragma unroll
        for (int t = 0; t < 5; ++t) {
            aq = mfma16(A[0][t], Bf[t], aq);
            ak = mfma16(A[1][t], Bf[t], ak);
            av = mfma16(A[2][t], Bf[t], av);
        }
        int w = w0 + pt * 16 + lr;
#pragma unroll
        for (int r = 0; r < 4; ++r) {
            int co = lg * 4 + r;
            size_t o = ((size_t)(b * CC + co) * FF + fglob) * WW + w;
            oq[o] = f2bf(aq[r]);
            ok[o] = f2bf(ak[r]);
            ov[o] = f2bf(av[r]);
        }
    }
}

// ---------------- MFMA per-channel GEMM, K-major input T[f][w] ----------------
template <int K, int M, int MODE>
__global__ __launch_bounds__(256, 4) void mgemm(
    const unsigned short* __restrict__ T, const float* __restrict__ Wt,
    unsigned short* __restrict__ ob, float* __restrict__ of) {
    __shared__ unsigned short Al[64 * 64];
    __shared__ unsigned short Bl[64 * 64];
    const int bc = blockIdx.x, c = bc & 15;
    const int G0 = blockIdx.y * 64, W0 = blockIdx.z * 64;
    const int tx = threadIdx.x;
    const int lane = tx & 63, wid = tx >> 6;
    const int lr = lane & 15, lg = lane >> 4;
    const int wr = wid >> 1, wc = wid & 1;
    const unsigned short* Tb = T + (size_t)bc * K * WW;
    const float* Wb = Wt + ((size_t)c * M + G0) * K;
    f32x4 acc[2][2];
#pragma unroll
    for (int i = 0; i < 2; ++i)
#pragma unroll
        for (int j = 0; j < 2; ++j) acc[i][j] = (f32x4){0.f, 0.f, 0.f, 0.f};
    const int ag = tx >> 2, aseg = tx & 3;
    const int bfr = tx >> 3, bws = tx & 7;
    for (int f0 = 0; f0 < K; f0 += 64) {
        {
            const float* wrow = Wb + (size_t)ag * K + f0 + aseg * 16;
            float4 x0 = *(const float4*)(wrow + 0);
            float4 x1 = *(const float4*)(wrow + 4);
            float4 x2 = *(const float4*)(wrow + 8);
            float4 x3 = *(const float4*)(wrow + 12);
            uint4 p0, p1;
            p0.x = f2bf(x0.x) | ((unsigned)f2bf(x0.y) << 16);
            p0.y = f2bf(x0.z) | ((unsigned)f2bf(x0.w) << 16);
            p0.z = f2bf(x1.x) | ((unsigned)f2bf(x1.y) << 16);
            p0.w = f2bf(x1.z) | ((unsigned)f2bf(x1.w) << 16);
            p1.x = f2bf(x2.x) | ((unsigned)f2bf(x2.y) << 16);
            p1.y = f2bf(x2.z) | ((unsigned)f2bf(x2.w) << 16);
            p1.z = f2bf(x3.x) | ((unsigned)f2bf(x3.y) << 16);
            p1.w = f2bf(x3.z) | ((unsigned)f2bf(x3.w) << 16);
            char* abase = (char*)Al + ag * 128;
            int sw = (ag & 7) << 4;
            *(uint4*)(abase + ((aseg * 32 + 0) ^ sw)) = p0;
            *(uint4*)(abase + ((aseg * 32 + 16) ^ sw)) = p1;
        }
        {
            char* bb = (char*)Bl;
#pragma unroll
            for (int half = 0; half < 2; ++half) {
                int ff = bfr + half * 32;
                us8 tv = *(const us8*)(Tb + (size_t)(f0 + ff) * WW + W0 + bws * 8);
#pragma unroll
                for (int j = 0; j < 8; ++j) {
                    int wloc = bws * 8 + j;
                    *(unsigned short*)(bb + wloc * 128 + ((ff * 2) ^ (j << 4))) = tv[j];
                }
            }
        }
        __syncthreads();
#pragma unroll
        for (int kc = 0; kc < 2; ++kc) {
            bf16x8 af[2], bf[2];
#pragma unroll
            for (int i = 0; i < 2; ++i) {
                int gr = wr * 32 + i * 16 + lr;
                af[i] = *(const bf16x8*)((char*)Al + gr * 128 + ((kc * 64 + lg * 16) ^ ((gr & 7) << 4)));
                int wrow2 = wc * 32 + i * 16 + lr;
                bf[i] = *(const bf16x8*)((char*)Bl + wrow2 * 128 + ((kc * 64 + lg * 16) ^ ((wrow2 & 7) << 4)));
            }
#pragma unroll
            for (int i = 0; i < 2; ++i)
#pragma unroll
                for (int j = 0; j < 2; ++j)
                    acc[i][j] = mfma16(af[i], bf[j], acc[i][j]);
        }
        __syncthreads();
    }
#pragma unroll
    for (int i = 0; i < 2; ++i)
#pragma unroll
        for (int j = 0; j < 2; ++j)
#pragma unroll
            for (int r = 0; r < 4; ++r) {
                int g = G0 + wr * 32 + i * 16 + lg * 4 + r;
                int w = W0 + wc * 32 + j * 16 + lr;
                size_t o = ((size_t)bc * M + g) * WW + w;
                if (MODE == 0) ob[o] = f2bf(acc[i][j][r]);
                else of[o] += acc[i][j][r];
            }
}

// ---------------- MFMA per-channel GEMM, N-major input Tt[w][f] ----------------
// MODE 0: bf16 [g][w]; MODE 1: f32 += [g][w]; MODE 2: bf16 transposed [w][g]
template <int K, int M, int MODE>
__global__ __launch_bounds__(256, 4) void mgemm_bt(
    const unsigned short* __restrict__ Tt, const float* __restrict__ Wt,
    unsigned short* __restrict__ ob, float* __restrict__ of) {
    __shared__ unsigned short Al[64 * 64];
    __shared__ unsigned short Bl[64 * 64];
    const int bc = blockIdx.x, c = bc & 15;
    const int G0 = blockIdx.y * 64, W0 = blockIdx.z * 64;
    const int tx = threadIdx.x;
    const int lane = tx & 63, wid = tx >> 6;
    const int lr = lane & 15, lg = lane >> 4;
    const int wr = wid >> 1, wc = wid & 1;
    const unsigned short* Tb = Tt + (size_t)bc * WW * K;
    const float* Wb = Wt + ((size_t)c * M + G0) * K;
    f32x4 acc[2][2];
#pragma unroll
    for (int i = 0; i < 2; ++i)
#pragma unroll
        for (int j = 0; j < 2; ++j) acc[i][j] = (f32x4){0.f, 0.f, 0.f, 0.f};
    const int ag = tx >> 2, aseg = tx & 3;
    for (int f0 = 0; f0 < K; f0 += 64) {
        {
            const float* wrow = Wb + (size_t)ag * K + f0 + aseg * 16;
            float4 x0 = *(const float4*)(wrow + 0);
            float4 x1 = *(const float4*)(wrow + 4);
            float4 x2 = *(const float4*)(wrow + 8);
            float4 x3 = *(const float4*)(wrow + 12);
            uint4 p0, p1;
            p0.x = f2bf(x0.x) | ((unsigned)f2bf(x0.y) << 16);
            p0.y = f2bf(x0.z) | ((unsigned)f2bf(x0.w) << 16);
            p0.z = f2bf(x1.x) | ((unsigned)f2bf(x1.y) << 16);
            p0.w = f2bf(x1.z) | ((unsigned)f2bf(x1.w) << 16);
            p1.x = f2bf(x2.x) | ((unsigned)f2bf(x2.y) << 16);
            p1.y = f2bf(x2.z) | ((unsigned)f2bf(x2.w) << 16);
            p1.z = f2bf(x3.x) | ((unsigned)f2bf(x3.y) << 16);
            p1.w = f2bf(x3.z) | ((unsigned)f2bf(x3.w) << 16);
            char* abase = (char*)Al + ag * 128;
            int sw = (ag & 7) << 4;
            *(uint4*)(abase + ((aseg * 32 + 0) ^ sw)) = p0;
            *(uint4*)(abase + ((aseg * 32 + 16) ^ sw)) = p1;
        }
        {
            const int seg = tx & 7;
#pragma unroll
            for (int rep = 0; rep < 2; ++rep) {
                int wrow = (tx >> 3) + rep * 32;
                us8 tv = *(const us8*)(Tb + (size_t)(W0 + wrow) * K + f0 + seg * 8);
                *(us8*)((char*)Bl + wrow * 128 + ((seg * 16) ^ ((wrow & 7) << 4))) = tv;
            }
        }
        __syncthreads();
#pragma unroll
        for (int kc = 0; kc < 2; ++kc) {
            bf16x8 af[2], bf[2];
#pragma unroll
            for (int i = 0; i < 2; ++i) {
                int gr = wr * 32 + i * 16 + lr;
                af[i] = *(const bf16x8*)((char*)Al + gr * 128 + ((kc * 64 + lg * 16) ^ ((gr & 7) << 4)));
                int wrow2 = wc * 32 + i * 16 + lr;
                bf[i] = *(const bf16x8*)((char*)Bl + wrow2 * 128 + ((kc * 64 + lg * 16) ^ ((wrow2 & 7) << 4)));
            }
#pragma unroll
            for (int i = 0; i < 2; ++i)
#pragma unroll
                for (int j = 0; j < 2; ++j)
                    acc[i][j] = mfma16(af[i], bf[j], acc[i][j]);
        }
        __syncthreads();
    }
    if (MODE == 2) {
#pragma unroll
        for (int i = 0; i < 2; ++i)
#pragma unroll
            for (int j = 0; j < 2; ++j) {
                int g = G0 + wr * 32 + i * 16 + lg * 4;
                int w = W0 + wc * 32 + j * 16 + lr;
                us4 pk;
                pk.x = f2bf(acc[i][j][0]); pk.y = f2bf(acc[i][j][1]);
                pk.z = f2bf(acc[i][j][2]); pk.w = f2bf(acc[i][j][3]);
                *(us4*)(ob + ((size_t)bc * WW + w) * M + g) = pk;
            }
    } else {
#pragma unroll
        for (int i = 0; i < 2; ++i)
#pragma unroll
            for (int j = 0; j < 2; ++j)
#pragma unroll
                for (int r = 0; r < 4; ++r) {
                    int g = G0 + wr * 32 + i * 16 + lg * 4 + r;
                    int w = W0 + wc * 32 + j * 16 + lr;
                    size_t o = ((size_t)bc * M + g) * WW + w;
                    if (MODE == 0) ob[o] = f2bf(acc[i][j][r]);
                    else of[o] += acc[i][j][r];
                }
    }
}

// ---------------- fused attention v3: register P, PV via shfl-assembled K=32 B-frags ----------------
// grid (BC*HH, 8). block 256 = 4 waves, wave owns 16 q rows. LDS 68KB -> 2 blocks/CU.
__global__ __launch_bounds__(256, 2) void attn_fused(
    const unsigned short* __restrict__ qb, const unsigned short* __restrict__ kb,
    const unsigned short* __restrict__ vb, float* __restrict__ qko,
    unsigned short* __restrict__ abT) {
    __shared__ unsigned short Kl[512 * 32];       // [kw][d], byte-XOR (kw&3)<<4
    __shared__ unsigned short Vl[32 * 512];       // [d][kw], byte-XOR (d&7)<<4
    __shared__ unsigned short Ql[64 * 32];        // [q][d]
    const int bch = blockIdx.x, qt = blockIdx.y;
    const int bc = bch >> 3, h = bch & 7;
    const int tx = threadIdx.x;
    const int lane = tx & 63, wid = tx >> 6;
    const int lr = lane & 15, lg = lane >> 4;

    const unsigned short* kbase = kb + ((size_t)bc * FF + h * DH) * WW;
    const unsigned short* vbase = vb + ((size_t)bc * FF + h * DH) * WW;
    const unsigned short* qbase = qb + ((size_t)bc * FF + h * DH) * WW + qt * 64;

    // stage K transposed -> Kl[kw][d]
    {
        int d0 = ((tx >> 3) & 7) * 4;
#pragma unroll
        for (int rep = 0; rep < 2; ++rep) {
            int kw0 = (tx & 7) * 8 + ((tx >> 6) & 3) * 64 + rep * 256;
            us8 v0 = *(const us8*)(kbase + (size_t)(d0 + 0) * WW + kw0);
            us8 v1 = *(const us8*)(kbase + (size_t)(d0 + 1) * WW + kw0);
            us8 v2 = *(const us8*)(kbase + (size_t)(d0 + 2) * WW + kw0);
            us8 v3 = *(const us8*)(kbase + (size_t)(d0 + 3) * WW + kw0);
#pragma unroll
            for (int j = 0; j < 8; ++j) {
                int kw = kw0 + j;
                us4 p; p.x = v0[j]; p.y = v1[j]; p.z = v2[j]; p.w = v3[j];
                *(us4*)((char*)Kl + kw * 64 + ((d0 * 2) ^ ((kw & 3) << 4))) = p;
            }
        }
    }
    // stage V -> Vl[d][kw]
    {
        int d = tx >> 3;
        int sw = (d & 7) << 4;
#pragma unroll
        for (int rep = 0; rep < 8; ++rep) {
            int kw0 = (tx & 7) * 8 + rep * 64;
            us8 tv = *(const us8*)(vbase + (size_t)d * WW + kw0);
            *(us8*)((char*)Vl + d * 1024 + ((kw0 * 2) ^ sw)) = tv;
        }
    }
    // stage Q transposed -> Ql[q][d]
    if (tx < 64) {
        int d0 = ((tx >> 3) & 7) * 4;
        int q0 = (tx & 7) * 8;
        us8 v0 = *(const us8*)(qbase + (size_t)(d0 + 0) * WW + q0);
        us8 v1 = *(const us8*)(qbase + (size_t)(d0 + 1) * WW + q0);
        us8 v2 = *(const us8*)(qbase + (size_t)(d0 + 2) * WW + q0);
        us8 v3 = *(const us8*)(qbase + (size_t)(d0 + 3) * WW + q0);
#pragma unroll
        for (int j = 0; j < 8; ++j) {
            us4 p; p.x = v0[j]; p.y = v1[j]; p.z = v2[j]; p.w = v3[j];
            *(us4*)(&Ql[(q0 + j) * 32 + d0]) = p;
        }
    }
    __syncthreads();

    const int q0w = wid * 16;
    bf16x8 qf = *(const bf16x8*)((char*)Ql + (q0w + lr) * 64 + lg * 16);
    f32x4 s[32];
#pragma unroll
    for (int i = 0; i < 32; ++i) s[i] = (f32x4){0.f, 0.f, 0.f, 0.f};
    // S^T[kw][q]: lane holds q=lr, kw = kwt*16 + lg*4 + r
#pragma unroll
    for (int kwt = 0; kwt < 32; ++kwt) {
        int krow = kwt * 16 + lr;
        bf16x8 kf = *(const bf16x8*)((char*)Kl + krow * 64 + ((lg * 16) ^ ((krow & 3) << 4)));
        s[kwt] = mfma16(kf, qf, s[kwt]);
    }
    // scale + direct qk store from accumulators + row max
    float mx = -3.0e38f;
    float* qrow = qko + ((size_t)bch * WW + qt * 64 + q0w + lr) * WW;
#pragma unroll
    for (int kwt = 0; kwt < 32; ++kwt) {
        s[kwt] *= 0.0625f;
        float4 st;
        st.x = s[kwt][0]; st.y = s[kwt][1]; st.z = s[kwt][2]; st.w = s[kwt][3];
        *(float4*)(qrow + kwt * 16 + lg * 4) = st;
        mx = fmaxf(mx, fmaxf(fmaxf(st.x, st.y), fmaxf(st.z, st.w)));
    }
    mx = fmaxf(mx, __shfl_xor(mx, 16));
    mx = fmaxf(mx, __shfl_xor(mx, 32));
    // exp & sum
    float sum = 0.f;
#pragma unroll
    for (int kwt = 0; kwt < 32; ++kwt) {
#pragma unroll
        for (int r = 0; r < 4; ++r) {
            float p = __expf(s[kwt][r] - mx);
            s[kwt][r] = p;
            sum += p;
        }
    }
    sum += __shfl_xor(sum, 16);
    sum += __shfl_xor(sum, 32);
    float inv = 1.0f / sum;

    // PV: assemble B-frag (8 consecutive kw per lane) from accumulator layout
    // (4 consecutive kw per lane) via XOR-16/32/48 lane exchange of packed bf16.
    f32x4 av[2];
    av[0] = (f32x4){0.f, 0.f, 0.f, 0.f};
    av[1] = (f32x4){0.f, 0.f, 0.f, 0.f};
#pragma unroll
    for (int t = 0; t < 16; ++t) {
        unsigned pa0 = f2bf(s[2 * t][0]) | ((unsigned)f2bf(s[2 * t][1]) << 16);
        unsigned pa1 = f2bf(s[2 * t][2]) | ((unsigned)f2bf(s[2 * t][3]) << 16);
        unsigned pb0 = f2bf(s[2 * t + 1][0]) | ((unsigned)f2bf(s[2 * t + 1][1]) << 16);
        unsigned pb1 = f2bf(s[2 * t + 1][2]) | ((unsigned)f2bf(s[2 * t + 1][3]) << 16);
        unsigned s16_0 = (lg == 1) ? pa0 : pb0, s16_1 = (lg == 1) ? pa1 : pb1;
        unsigned s32_0 = (lg == 3) ? pa0 : pb0, s32_1 = (lg == 3) ? pa1 : pb1;
        unsigned s48_0 = (lg == 2) ? pa0 : pb0, s48_1 = (lg == 2) ? pa1 : pb1;
        unsigned r16_0 = (unsigned)__shfl_xor((int)s16_0, 16);
        unsigned r16_1 = (unsigned)__shfl_xor((int)s16_1, 16);
        unsigned r32_0 = (unsigned)__shfl_xor((int)s32_0, 32);
        unsigned r32_1 = (unsigned)__shfl_xor((int)s32_1, 32);
        unsigned r48_0 = (unsigned)__shfl_xor((int)s48_0, 48);
        unsigned r48_1 = (unsigned)__shfl_xor((int)s48_1, 48);
        uint4 wv;
        if (lg == 0)      { wv.x = pa0;   wv.y = pa1;   wv.z = r16_0; wv.w = r16_1; }
        else if (lg == 1) { wv.x = r48_0; wv.y = r48_1; wv.z = r32_0; wv.w = r32_1; }
        else if (lg == 2) { wv.x = r32_0; wv.y = r32_1; wv.z = r48_0; wv.w = r48_1; }
        else              { wv.x = r16_0; wv.y = r16_1; wv.z = pb0;  wv.w = pb1; }
        bf16x8 pf = *reinterpret_cast<bf16x8*>(&wv);
#pragma unroll
        for (int di = 0; di < 2; ++di) {
            int vr = di * 16 + lr;
            bf16x8 vf = *(const bf16x8*)((char*)Vl + vr * 1024 + ((t * 64 + lg * 16) ^ ((vr & 7) << 4)));
            av[di] = mfma16(vf, pf, av[di]);
        }
    }
    // store a TRANSPOSED [w][d]: lane holds q=lr, 4 consecutive d = di*16+lg*4+r
    unsigned short* arow = abT + ((size_t)bc * WW + qt * 64 + q0w + lr) * FF + h * DH;
#pragma unroll
    for (int di = 0; di < 2; ++di) {
        us4 pk;
        pk.x = f2bf(av[di][0] * inv); pk.y = f2bf(av[di][1] * inv);
        pk.z = f2bf(av[di][2] * inv); pk.w = f2bf(av[di][3] * inv);
        *(us4*)(arow + di * 16 + lg * 4) = pk;
    }
}

// ---------------- LDS-tiled depthwise 16-ch mix ----------------
template <int NPC, int MODE>
__global__ __launch_bounds__(256) void dwmix(
    const unsigned short* __restrict__ in, const float* __restrict__ wdw,
    const float* __restrict__ x, float* __restrict__ fo, unsigned short* __restrict__ bo) {
    __shared__ unsigned short L[16][1024];
    int b = blockIdx.y;
    size_t base = (size_t)blockIdx.x * 1024;
    int tx = threadIdx.x;
#pragma unroll
    for (int r = 0; r < 8; ++r) {
        int idx = tx + r * 256;
        int ci = idx >> 7;
        int seg = idx & 127;
        *(us8*)&L[ci][seg * 8] = *(const us8*)(in + ((size_t)(b * 16 + ci)) * NPC + base + seg * 8);
    }
    __syncthreads();
#pragma unroll
    for (int pos = 0; pos < 4; ++pos) {
        int fw = tx + pos * 256;
        float vin[16];
#pragma unroll
        for (int ci = 0; ci < 16; ++ci) vin[ci] = bf2f(L[ci][fw]);
#pragma unroll
        for (int o = 0; o < 16; ++o) {
            float s = 0.f;
#pragma unroll
            for (int ci = 0; ci < 16; ++ci) s += wdw[o * 16 + ci] * vin[ci];
            size_t oi = ((size_t)(b * 16 + o)) * NPC + base + fw;
            if (MODE == 0) fo[oi] = x[oi] + s;
            else { s = fmaxf(s, 0.f); bo[oi] = f2bf(s * s); }
        }
    }
}

extern "C" void kernel_launch(void* const* d_in, const int* in_sizes, int n_in,
                              void* d_out, int out_size, void* d_ws, size_t ws_size,
                              hipStream_t stream) {
    const float* x      = (const float*)d_in[0];
    const float* conv_q = (const float*)d_in[1];
    const float* conv_k = (const float*)d_in[2];
    const float* conv_v = (const float*)d_in[3];
    const float* wq     = (const float*)d_in[4];
    const float* wk     = (const float*)d_in[5];
    const float* wv     = (const float*)d_in[6];
    const float* wo_pw  = (const float*)d_in[7];
    const float* wo_dw  = (const float*)d_in[8];
    const float* g1     = (const float*)d_in[9];
    const float* b1     = (const float*)d_in[10];
    const float* g2     = (const float*)d_in[11];
    const float* b2     = (const float*)d_in[12];
    const float* w1_pw  = (const float*)d_in[13];
    const float* w1_dw  = (const float*)d_in[14];
    const float* w2_pw  = (const float*)d_in[15];

    float* hout  = (float*)d_out;
    float* qkout = (float*)d_out + 4194304;

    char* ws = (char*)d_ws;
    const size_t MB8 = (size_t)8 << 20;
    unsigned short* n1  = (unsigned short*)(ws + 0 * MB8);   // later: abT
    unsigned short* cq  = (unsigned short*)(ws + 1 * MB8);   // later: pwb
    unsigned short* ck  = (unsigned short*)(ws + 2 * MB8);   // later: n2t
    unsigned short* cv  = (unsigned short*)(ws + 3 * MB8);
    unsigned short* qb  = (unsigned short*)(ws + 4 * MB8);
    unsigned short* kb  = (unsigned short*)(ws + 5 * MB8);
    unsigned short* vb  = (unsigned short*)(ws + 6 * MB8);
    unsigned short* u1t = (unsigned short*)(ws + 3 * MB8);   // 32 MB (cv/qb/kb/vb dead)
    unsigned short* u2t = (unsigned short*)(ws + 7 * MB8);   // 32 MB
    unsigned short* Awb = (unsigned short*)(ws + 7 * MB8);   // 15 KB, dead before u2t
    unsigned short* abT = n1;
    unsigned short* pwb = cq;
    unsigned short* n2t = ck;

    ln_kernel<<<dim3(BC, 2), 256, 0, stream>>>(x, g1, b1, n1);
    wrepack<<<dim3(30), 256, 0, stream>>>(conv_q, conv_k, conv_v, Awb);
    conv3_mfma<<<dim3(8, 64, BB), 256, 0, stream>>>(n1, Awb, cq, ck, cv);
    mgemm<256, 256, 0><<<dim3(BC, 4, 8), 256, 0, stream>>>(cq, wq, qb, nullptr);
    mgemm<256, 256, 0><<<dim3(BC, 4, 8), 256, 0, stream>>>(ck, wk, kb, nullptr);
    mgemm<256, 256, 0><<<dim3(BC, 4, 8), 256, 0, stream>>>(cv, wv, vb, nullptr);
    attn_fused<<<dim3(BC * HH, 8), 256, 0, stream>>>(qb, kb, vb, qkout, abT);
    mgemm_bt<256, 256, 0><<<dim3(BC, 4, 8), 256, 0, stream>>>(abT, wo_pw, pwb, nullptr);
    dwmix<131072, 0><<<dim3(128, BB), 256, 0, stream>>>(pwb, wo_dw, x, hout, nullptr);
    ln_t_kernel<<<dim3(BC, 2), 256, 0, stream>>>(hout, g2, b2, n2t);
    mgemm_bt<256, 1024, 2><<<dim3(BC, 16, 8), 256, 0, stream>>>(n2t, w1_pw, u1t, nullptr);
    dwmix<524288, 1><<<dim3(512, BB), 256, 0, stream>>>(u1t, w1_dw, nullptr, nullptr, u2t);
    mgemm_bt<1024, 256, 1><<<dim3(BC, 4, 8), 256, 0, stream>>>(u2t, w2_pw, nullptr, hout);
}